// Round 10
// baseline (279.627 us; speedup 1.0000x reference)
//
#include <hip/hip_runtime.h>

// LSTM B=4096, T=512, I=1, H=32 — MFMA, round 10: ILP-2 (two quads per wave).
//
// Block = 128 threads = 2 waves serving 8 batches as TWO independent quads
// P,Q (4 batches each). 512 blocks -> 1024 waves = 1/SIMD; the two quads'
// dependency chains (LDS round-trip, MFMA pairs, 3-stage trans chains)
// interleave inside each wave, hiding each other's latency; one barrier and
// one loop iteration serve both quads.
//
// Per-quad mapping = verified r8/r9: mfma_f32_16x16x32_bf16, batch b at
// A-rows {2b (h_hi), 2b+1 (h_lo)} (rows r%4 in {2,3} alias rows 0/1 and feed
// D regs 2,3 which are never read); wave w owns cells col+16w via its 4 gate
// tiles {w,w+2,w+4,w+6}; k-perm cell c <-> k=2*(c&15)+(c>>4); gate input
// scales (-log2e / -2log2e) folded into W_hh/W_ih/bias; double-buffered LDS,
// one __syncthreads per step. Weights/bias registers shared by both quads.

typedef float f32x4 __attribute__((ext_vector_type(4)));
typedef short s16x8 __attribute__((ext_vector_type(8)));

#define L2E 1.44269504088896340736f
#define MFMA(a, b, c) __builtin_amdgcn_mfma_f32_16x16x32_bf16((a), (b), (c), 0, 0, 0)

__device__ __forceinline__ unsigned bfpack(float a, float b) {
    return __builtin_amdgcn_perm(__float_as_uint(b), __float_as_uint(a), 0x07060302u);
}
__device__ __forceinline__ float hi_f(float f) {
    return __uint_as_float(__float_as_uint(f) & 0xFFFF0000u);
}
__device__ __forceinline__ float sig_pre(float t) {   // t = -L2E*g
    return __builtin_amdgcn_rcpf(1.0f + __builtin_amdgcn_exp2f(t));
}
__device__ __forceinline__ float tanh_pre(float t) {  // t = -2*L2E*g
    return fmaf(__builtin_amdgcn_rcpf(1.0f + __builtin_amdgcn_exp2f(t)), 2.0f, -1.0f);
}

#define RSTR 40   // u16 row stride: 20 words -> the 8 live rows' b128 reads
                  // tile the 32 banks exactly once per 16-lane phase

__global__ __launch_bounds__(128, 1) void lstm_mfma_kernel(
    const float* __restrict__ x,      // [B, 512]
    const float* __restrict__ W_ih,   // [128]
    const float* __restrict__ W_hh,   // [128, 32]
    const float* __restrict__ b_ih,   // [128]
    const float* __restrict__ b_hh,   // [128]
    const float* __restrict__ W_lin,  // [32]
    const float* __restrict__ b_lin,  // [1]
    float* __restrict__ out,          // [B]
    int B)
{
    __shared__ unsigned short Hb[2][2][8][RSTR];  // [quad][buf][2*batch+hl][RSTR]
    __shared__ float plds[2][4][2];

    const int tid  = (int)threadIdx.x;
    const int w    = tid >> 6;            // wave 0/1 -> cells col / col+16
    const int lane = tid & 63;
    const int col  = lane & 15;           // tile col
    const int g    = lane >> 4;           // batch slot & k-group

    // zero both quads' buffers (h(0) = 0)
    for (int i = tid; i < 2 * 2 * 8 * RSTR; i += 128)
        ((unsigned short*)Hb)[i] = 0;

    // A-row: col%4==0 -> hi(batch col/4); ==1 -> lo; ==2/3 -> alias rows 0/1
    const int m4   = col & 3;
    const int rrow = (m4 == 0) ? 2 * (col >> 2)
                   : (m4 == 1) ? 2 * (col >> 2) + 1
                   : (m4 - 2);
    const unsigned short* ArdP0 = &Hb[0][0][rrow][8 * g];
    const unsigned short* ArdP1 = &Hb[0][1][rrow][8 * g];
    const unsigned short* ArdQ0 = &Hb[1][0][rrow][8 * g];
    const unsigned short* ArdQ1 = &Hb[1][1][rrow][8 * g];

    // h publish: this lane's cell -> u16 at k = 2*col + w, rows (g,hi),(g,lo)
    unsigned short* WhiP0 = &Hb[0][0][2 * g + 0][2 * col + w];
    unsigned short* WloP0 = &Hb[0][0][2 * g + 1][2 * col + w];
    unsigned short* WhiP1 = &Hb[0][1][2 * g + 0][2 * col + w];
    unsigned short* WloP1 = &Hb[0][1][2 * g + 1][2 * col + w];
    unsigned short* WhiQ0 = &Hb[1][0][2 * g + 0][2 * col + w];
    unsigned short* WloQ0 = &Hb[1][0][2 * g + 1][2 * col + w];
    unsigned short* WhiQ1 = &Hb[1][1][2 * g + 0][2 * col + w];
    unsigned short* WloQ1 = &Hb[1][1][2 * g + 1][2 * col + w];

    // B-fragments for this wave's 4 tiles (t = w+2j; j = i,f,G,o), scales
    // folded; shared by both quads. u32 jj = pair(cell g*4+jj, g*4+jj+16).
    s16x8 bhi[4], blo[4];
    float wihs[4];
    f32x4 biasC[4];
#pragma unroll
    for (int j = 0; j < 4; ++j) {
        const int t  = w + 2 * j;
        const int gr = t * 16 + col;
        const float sc = (j == 2) ? (-2.0f * L2E) : (-L2E);
        const float* wr = &W_hh[gr * 32];
        float4 wA = *reinterpret_cast<const float4*>(&wr[g * 4]);
        float4 wB = *reinterpret_cast<const float4*>(&wr[g * 4 + 16]);
        const float a0 = wA.x * sc, a1 = wA.y * sc, a2 = wA.z * sc, a3 = wA.w * sc;
        const float b0 = wB.x * sc, b1 = wB.y * sc, b2 = wB.z * sc, b3 = wB.w * sc;
        union { unsigned u[4]; s16x8 s; } H, L;
        H.u[0] = bfpack(a0, b0); H.u[1] = bfpack(a1, b1);
        H.u[2] = bfpack(a2, b2); H.u[3] = bfpack(a3, b3);
        L.u[0] = bfpack(a0 - hi_f(a0), b0 - hi_f(b0));
        L.u[1] = bfpack(a1 - hi_f(a1), b1 - hi_f(b1));
        L.u[2] = bfpack(a2 - hi_f(a2), b2 - hi_f(b2));
        L.u[3] = bfpack(a3 - hi_f(a3), b3 - hi_f(b3));
        bhi[j] = H.s; blo[j] = L.s;
        wihs[j] = W_ih[gr] * sc;
        const float bb = (b_ih[gr] + b_hh[gr]) * sc;
        biasC[j] = f32x4{bb, 0.0f, 0.0f, 0.0f};       // bias only in reg0 (hi row)
    }

    const int bP = blockIdx.x * 8 + g;          // quad P batch
    const int bQ = bP + 4;                      // quad Q batch
    const int bPc = bP < B ? bP : (B - 1);
    const int bQc = bQ < B ? bQ : (B - 1);
    const float* xbP = x + (size_t)bPc * 512;
    const float* xbQ = x + (size_t)bQc * 512;

    float4 xAP = *reinterpret_cast<const float4*>(xbP);
    float4 xBP = *reinterpret_cast<const float4*>(xbP + 4);
    float4 xAQ = *reinterpret_cast<const float4*>(xbQ);
    float4 xBQ = *reinterpret_cast<const float4*>(xbQ + 4);

    float cP = 0.0f, hP = 0.0f, cQ = 0.0f, hQ = 0.0f;
    __syncthreads();                                   // zero-init visible

    for (int tc = 0; tc < 64; ++tc) {
        const int nbase = ((tc + 1) & 63) * 8;
        const float4 nAP = *reinterpret_cast<const float4*>(xbP + nbase);
        const float4 nBP = *reinterpret_cast<const float4*>(xbP + nbase + 4);
        const float4 nAQ = *reinterpret_cast<const float4*>(xbQ + nbase);
        const float4 nBQ = *reinterpret_cast<const float4*>(xbQ + nbase + 4);
        const float xtsP[8] = {xAP.x, xAP.y, xAP.z, xAP.w, xBP.x, xBP.y, xBP.z, xBP.w};
        const float xtsQ[8] = {xAQ.x, xAQ.y, xAQ.z, xAQ.w, xBQ.x, xBQ.y, xBQ.z, xBQ.w};

#pragma unroll
        for (int s = 0; s < 8; ++s) {
            // even global step reads buf0, writes buf1 (static after unroll)
            const s16x8 afP = *reinterpret_cast<const s16x8*>((s & 1) ? ArdP1 : ArdP0);
            const s16x8 afQ = *reinterpret_cast<const s16x8*>((s & 1) ? ArdQ1 : ArdQ0);

            f32x4 aP[4], aQ[4];
#pragma unroll
            for (int j = 0; j < 4; ++j) aP[j] = MFMA(afP, bhi[j], biasC[j]);
#pragma unroll
            for (int j = 0; j < 4; ++j) aQ[j] = MFMA(afQ, bhi[j], biasC[j]);
#pragma unroll
            for (int j = 0; j < 4; ++j) aP[j] = MFMA(afP, blo[j], aP[j]);
#pragma unroll
            for (int j = 0; j < 4; ++j) aQ[j] = MFMA(afQ, blo[j], aQ[j]);

            float gP[4], gQ[4];
#pragma unroll
            for (int j = 0; j < 4; ++j) gP[j] = fmaf(xtsP[s], wihs[j], aP[j][0] + aP[j][1]);
#pragma unroll
            for (int j = 0; j < 4; ++j) gQ[j] = fmaf(xtsQ[s], wihs[j], aQ[j][0] + aQ[j][1]);

            // interleaved independent nonlinearity chains (P and Q)
            const float iP = sig_pre(gP[0]),  iQ = sig_pre(gQ[0]);
            const float fP = sig_pre(gP[1]),  fQ = sig_pre(gQ[1]);
            const float GP = tanh_pre(gP[2]), GQ = tanh_pre(gQ[2]);
            const float oP = sig_pre(gP[3]),  oQ = sig_pre(gQ[3]);

            cP = fmaf(fP, cP, iP * GP);
            cQ = fmaf(fQ, cQ, iQ * GQ);
            hP = oP * tanh_pre(cP * (-2.0f * L2E));
            hQ = oQ * tanh_pre(cQ * (-2.0f * L2E));

            // publish h (hi + residual-lo bf16) to the OTHER buffer
            const unsigned uP = __float_as_uint(hP);
            const float lP = hP - __uint_as_float(uP & 0xFFFF0000u);
            const unsigned uQ = __float_as_uint(hQ);
            const float lQ = hQ - __uint_as_float(uQ & 0xFFFF0000u);
            *((s & 1) ? WhiP0 : WhiP1) = (unsigned short)(uP >> 16);
            *((s & 1) ? WloP0 : WloP1) = (unsigned short)(__float_as_uint(lP) >> 16);
            *((s & 1) ? WhiQ0 : WhiQ1) = (unsigned short)(uQ >> 16);
            *((s & 1) ? WloQ0 : WloQ1) = (unsigned short)(__float_as_uint(lQ) >> 16);
            __syncthreads();
        }
        xAP = nAP; xBP = nBP; xAQ = nAQ; xBQ = nBQ;
    }

    // out[b] = sum_cells h*W_lin + b_lin: 16-lane reduce, then cross-wave
    float pPv = hP * W_lin[col + 16 * w];
    float pQv = hQ * W_lin[col + 16 * w];
#pragma unroll
    for (int off = 8; off; off >>= 1) {
        pPv += __shfl_xor(pPv, off, 64);
        pQv += __shfl_xor(pQv, off, 64);
    }
    if (col == 0) { plds[0][g][w] = pPv; plds[1][g][w] = pQv; }
    __syncthreads();
    if (w == 0 && col == 0) {
        if (bP < B) out[bP] = plds[0][g][0] + plds[0][g][1] + b_lin[0];
        if (bQ < B) out[bQ] = plds[1][g][0] + plds[1][g][1] + b_lin[0];
    }
}

extern "C" void kernel_launch(void* const* d_in, const int* in_sizes, int n_in,
                              void* d_out, int out_size, void* d_ws, size_t ws_size,
                              hipStream_t stream) {
    const float* x     = (const float*)d_in[0];
    const float* W_ih  = (const float*)d_in[1];
    const float* W_hh  = (const float*)d_in[2];
    const float* b_ih  = (const float*)d_in[3];
    const float* b_hh  = (const float*)d_in[4];
    const float* W_lin = (const float*)d_in[5];
    const float* b_lin = (const float*)d_in[6];
    float* out = (float*)d_out;

    const int B = in_sizes[0] / 512;          // x is [B, 512, 1]
    const int blocks = (B + 7) / 8;           // 8 batches per 128-thread block

    lstm_mfma_kernel<<<blocks, 128, 0, stream>>>(x, W_ih, W_hh, b_ih, b_hh,
                                                 W_lin, b_lin, out, B);
}

// Round 11
// 131.370 us; speedup vs baseline: 2.1285x; 2.1285x over previous
//
#include <hip/hip_runtime.h>

// LSTM B=4096, T=512, I=1, H=32 — MFMA, round 11: r9 base + fp16 single-pass B.
//
// r10 post-mortem: ILP-2 halved waves (2048->1024) betting on compiler ILP;
// compiler serialized the two chains (VGPR 76) -> 2x regression. Reverted.
//
// Structure (verified r9, 145us): block = 128 threads = 2 waves sharing 4
// batches. Wave w owns cells col+16w (one cell per lane) via its 4 gate tiles
// {w,w+2,w+4,w+6}. A-rows (indexed by col): {4b,4b+1} = batch b h_hi,h_lo
// (cols with col%4 in {2,3} alias rows 0/1, feeding D regs 2,3 never read);
// D: lane (col,g) reg0 = h_hi dot, reg1 = h_lo dot of batch g. k-perm:
// cell c <-> k = 2*(c&15)+(c>>4). Double-buffered LDS, 1 __syncthreads/step.
//
// NEW (r11): fp16 instead of bf16. W*scale fits fp16 with ulp<=2^-13 ->
// per-gate error ~5e-5 (BELOW the r6 bf16 3-term scheme that passed at
// 9.8e-4). h carried as fp16 hi/lo in A-rows (error 2^-22). So B needs ONE
// fragment: 4 MFMAs/wave-step (was 8), dep depth 1 (was 2).
// Gate input scales (-log2e/-2log2e) folded into W_hh/W_ih/bias.

typedef float f32x4 __attribute__((ext_vector_type(4)));
typedef _Float16 f16x8 __attribute__((ext_vector_type(8)));

#define L2E 1.44269504088896340736f
#define MFMA16(a, b, c) __builtin_amdgcn_mfma_f32_16x16x32_f16((a), (b), (c), 0, 0, 0)

union H2U { _Float16 h; unsigned short u; };

__device__ __forceinline__ unsigned short f2h_u16(float f) {
    H2U v; v.h = (_Float16)f; return v.u;
}

__device__ __forceinline__ float sig_pre(float t) {   // t = -L2E*g
    return __builtin_amdgcn_rcpf(1.0f + __builtin_amdgcn_exp2f(t));
}
__device__ __forceinline__ float tanh_pre(float t) {  // t = -2*L2E*g
    return fmaf(__builtin_amdgcn_rcpf(1.0f + __builtin_amdgcn_exp2f(t)), 2.0f, -1.0f);
}

#define RSTR 40   // u16 row stride: 80B rows, 16B-aligned, banks spread

__global__ __launch_bounds__(128, 2) void lstm_mfma_kernel(
    const float* __restrict__ x,      // [B, 512]
    const float* __restrict__ W_ih,   // [128]
    const float* __restrict__ W_hh,   // [128, 32]
    const float* __restrict__ b_ih,   // [128]
    const float* __restrict__ b_hh,   // [128]
    const float* __restrict__ W_lin,  // [32]
    const float* __restrict__ b_lin,  // [1]
    float* __restrict__ out,          // [B]
    int B)
{
    __shared__ unsigned short Hb[2][8][RSTR];   // [buf][2*batch + hi/lo][RSTR]
    __shared__ float plds[4][2];

    const int tid  = (int)threadIdx.x;
    const int w    = tid >> 6;            // wave 0/1 -> cells col / col+16
    const int lane = tid & 63;
    const int col  = lane & 15;           // tile col = A-row index
    const int g    = lane >> 4;           // batch slot & k-group

    // zero both buffers (h(0) = 0; u16 0 == +0.0 in fp16)
    for (int i = tid; i < 2 * 8 * RSTR; i += 128)
        ((unsigned short*)Hb)[i] = 0;

    // A-row content: col%4==0 -> hi(batch col/4); ==1 -> lo; ==2/3 -> alias rows 0/1
    const int m4   = col & 3;
    const int rrow = (m4 == 0) ? 2 * (col >> 2)
                   : (m4 == 1) ? 2 * (col >> 2) + 1
                   : (m4 - 2);
    const unsigned short* Ard0 = &Hb[0][rrow][8 * g];   // 16B-aligned
    const unsigned short* Ard1 = &Hb[1][rrow][8 * g];

    // h publish: this lane's cell -> u16 at k = 2*col + w, rows (g,hi),(g,lo)
    unsigned short* Whi0 = &Hb[0][2 * g + 0][2 * col + w];
    unsigned short* Wlo0 = &Hb[0][2 * g + 1][2 * col + w];
    unsigned short* Whi1 = &Hb[1][2 * g + 0][2 * col + w];
    unsigned short* Wlo1 = &Hb[1][2 * g + 1][2 * col + w];

    // B-fragments for this wave's 4 tiles (t = w+2j; j = i,f,G,o): fp16,
    // scales folded. u16 pair jj = (cell g*4+jj, cell g*4+jj+16)  [k-perm]
    f16x8 bf[4];
    float wihs[4];
    f32x4 biasC[4];
#pragma unroll
    for (int j = 0; j < 4; ++j) {
        const int t  = w + 2 * j;
        const int gr = t * 16 + col;
        const float sc = (j == 2) ? (-2.0f * L2E) : (-L2E);
        const float* wr = &W_hh[gr * 32];
        float4 wA = *reinterpret_cast<const float4*>(&wr[g * 4]);       // cells g4+0..3
        float4 wB = *reinterpret_cast<const float4*>(&wr[g * 4 + 16]);  // cells g4+16..19
        f16x8 bb;
        bb[0] = (_Float16)(wA.x * sc); bb[1] = (_Float16)(wB.x * sc);
        bb[2] = (_Float16)(wA.y * sc); bb[3] = (_Float16)(wB.y * sc);
        bb[4] = (_Float16)(wA.z * sc); bb[5] = (_Float16)(wB.z * sc);
        bb[6] = (_Float16)(wA.w * sc); bb[7] = (_Float16)(wB.w * sc);
        bf[j] = bb;
        wihs[j] = W_ih[gr] * sc;
        const float bbias = (b_ih[gr] + b_hh[gr]) * sc;
        biasC[j] = f32x4{bbias, 0.0f, 0.0f, 0.0f};     // bias only in reg0 (hi row)
    }

    const int b_glob = blockIdx.x * 4 + g;
    const int bc     = b_glob < B ? b_glob : (B - 1);
    const float* xb  = x + (size_t)bc * 512;

    float4 xA = *reinterpret_cast<const float4*>(xb);
    float4 xB = *reinterpret_cast<const float4*>(xb + 4);

    float cc = 0.0f, hh = 0.0f;
    __syncthreads();                                    // zero-init visible

    for (int tc = 0; tc < 64; ++tc) {
        const int nbase = ((tc + 1) & 63) * 8;
        const float4 nA = *reinterpret_cast<const float4*>(xb + nbase);
        const float4 nB = *reinterpret_cast<const float4*>(xb + nbase + 4);
        const float xts[8] = {xA.x, xA.y, xA.z, xA.w, xB.x, xB.y, xB.z, xB.w};

#pragma unroll
        for (int s = 0; s < 8; ++s) {
            const float xt = xts[s];

            // even global step reads buf0 (h starts in buf0), writes buf1
            const f16x8 af = *reinterpret_cast<const f16x8*>((s & 1) ? Ard1 : Ard0);

            // single pass: 4 independent MFMAs; reg0 = h_hi*W (+bias), reg1 = h_lo*W
            f32x4 acc[4];
#pragma unroll
            for (int j = 0; j < 4; ++j) acc[j] = MFMA16(af, bf[j], biasC[j]);

            float gt[4];
#pragma unroll
            for (int j = 0; j < 4; ++j)
                gt[j] = fmaf(xt, wihs[j], acc[j][0] + acc[j][1]);

            const float i_ = sig_pre(gt[0]);
            const float f_ = sig_pre(gt[1]);
            const float G_ = tanh_pre(gt[2]);
            const float o_ = sig_pre(gt[3]);

            cc = fmaf(f_, cc, i_ * G_);
            hh = o_ * tanh_pre(cc * (-2.0f * L2E));

            // publish h as fp16 hi + residual lo to the OTHER buffer
            H2U hi; hi.h = (_Float16)hh;
            const float lo_f = hh - (float)hi.h;
            *((s & 1) ? Whi0 : Whi1) = hi.u;
            *((s & 1) ? Wlo0 : Wlo1) = f2h_u16(lo_f);
            __syncthreads();
        }
        xA = nA; xB = nB;
    }

    // out[b] = sum_cells h*W_lin + b_lin: 16-lane reduce, then cross-wave via LDS
    float part = hh * W_lin[col + 16 * w];
#pragma unroll
    for (int off = 8; off; off >>= 1) part += __shfl_xor(part, off, 64);
    if (col == 0) plds[g][w] = part;
    __syncthreads();
    if (w == 0 && col == 0 && b_glob < B)
        out[b_glob] = plds[g][0] + plds[g][1] + b_lin[0];
}

extern "C" void kernel_launch(void* const* d_in, const int* in_sizes, int n_in,
                              void* d_out, int out_size, void* d_ws, size_t ws_size,
                              hipStream_t stream) {
    const float* x     = (const float*)d_in[0];
    const float* W_ih  = (const float*)d_in[1];
    const float* W_hh  = (const float*)d_in[2];
    const float* b_ih  = (const float*)d_in[3];
    const float* b_hh  = (const float*)d_in[4];
    const float* W_lin = (const float*)d_in[5];
    const float* b_lin = (const float*)d_in[6];
    float* out = (float*)d_out;

    const int B = in_sizes[0] / 512;          // x is [B, 512, 1]
    const int blocks = (B + 3) / 4;           // 4 batches per 128-thread block

    lstm_mfma_kernel<<<blocks, 128, 0, stream>>>(x, W_ih, W_hh, b_ih, b_hh,
                                                 W_lin, b_lin, out, B);
}